// Round 5
// baseline (456.949 us; speedup 1.0000x reference)
//
#include <hip/hip_runtime.h>
#include <math.h>

#define BB 256
#define NN 65536
#define NT 1024
#define CAP 3072
#define MARGIN 4e-3f

// Monotonic map: float order == uint order (ascending), and inverse
__device__ __forceinline__ unsigned int f2sort(float f) {
    unsigned int b = __float_as_uint(f);
    return (b & 0x80000000u) ? ~b : (b | 0x80000000u);
}
__device__ __forceinline__ float sort2f(unsigned int u) {
    unsigned int b = (u & 0x80000000u) ? (u & 0x7fffffffu) : ~u;
    return __uint_as_float(b);
}

// Bit-exact vs numpy f32 (f64 log rounded to f32) — only used near the cutoff
__device__ __forceinline__ unsigned int wexact(float u, float d) {
    float t1 = u + 1e-7f;
    float t2 = (float)log((double)t1);
    float t3 = (-t2) + 1e-7f;
    float G  = -(float)log((double)t3);
    float lgD = (float)log((double)d);
    return f2sort(G + lgD);
}

// Fast path: hw v_log_f32. |wfast - wexact| <= ~5e-5 abs for any element whose
// weight is near the cutoff (error relative; t3 >= |log t1| keeps it bounded).
__device__ __forceinline__ unsigned int wfast(float u, float d) {
    float t1 = u + 1e-7f;
    float t3 = -__logf(t1) + 1e-7f;
    float G  = -__logf(t3);
    return f2sort(G + __logf(d));
}

__device__ __forceinline__ bool finite_f(float f) {
    return (__float_as_uint(f) & 0x7f800000u) != 0x7f800000u;
}

// exact stable top-kb membership among the band (desc value, asc index)
__device__ __forceinline__ bool band_in(int idx, const unsigned int* bU,
                                        const int* bIdx, int cnt, int kb) {
    unsigned int me = 0u;
    for (int j = 0; j < cnt; j++) if (bIdx[j] == idx) { me = bU[j]; break; }
    int r = 0;
    for (int j = 0; j < cnt; j++) {
        unsigned int o = bU[j];
        r += (int)((o > me) || (o == me && bIdx[j] < idx));
    }
    return r < kb;
}

#define CHUNKS(OP) OP(0) OP(1) OP(2) OP(3) OP(4) OP(5) OP(6) OP(7) \
                   OP(8) OP(9) OP(10) OP(11) OP(12) OP(13) OP(14) OP(15)

// ---- radix-select phase macros (used by both approx and exact paths) ----
#define PASS1SEL(KKV) \
    { const int b0 = tid * 8; unsigned int cs = 0; \
      _Pragma("unroll") for (int i = 0; i < 8; i++) cs += hist[b0 + i]; \
      chunkSum[tid] = cs; } \
    __syncthreads(); \
    if (tid < 64) { \
        const int c0i = lane * 16; unsigned int s = 0; \
        _Pragma("unroll") for (int i = 0; i < 16; i++) s += chunkSum[c0i + i]; \
        unsigned int suf = s; \
        _Pragma("unroll") for (int off = 1; off < 64; off <<= 1) { \
            unsigned int tv = __shfl_down(suf, off); if (lane + off < 64) suf += tv; } \
        unsigned int above = suf - s; \
        if (suf >= (KKV) && above < (KKV)) { \
            unsigned int cum = above; \
            for (int ci = c0i + 15; ci >= c0i; ci--) { \
                unsigned int cch = chunkSum[ci]; \
                if (cum + cch >= (KKV)) { \
                    for (int b = ci * 8 + 7; ; b--) { \
                        unsigned int c2 = hist[b]; \
                        if (cum + c2 >= (KKV)) { s_sel = (unsigned int)b; s_kneed = (KKV) - cum; s_eq = c2; break; } \
                        cum += c2; } \
                    break; } \
                cum += cch; } } } \
    __syncthreads();

#define PASS2SEL(P, KN) \
    if (tid < 64) { \
        const int c0i = lane * 16; unsigned int s = 0; \
        _Pragma("unroll") for (int i = 0; i < 16; i++) s += hist[c0i + i]; \
        unsigned int suf = s; \
        _Pragma("unroll") for (int off = 1; off < 64; off <<= 1) { \
            unsigned int tv = __shfl_down(suf, off); if (lane + off < 64) suf += tv; } \
        unsigned int above = suf - s; \
        if (suf >= (KN) && above < (KN)) { \
            unsigned int cum = above; \
            for (int b = c0i + 15; ; b--) { \
                unsigned int c2 = hist[b]; \
                if (cum + c2 >= (KN)) { s_sel = ((P) << 10) | (unsigned int)b; s_kneed = (KN) - cum; s_eq = c2; break; } \
                cum += c2; } } } \
    __syncthreads();

#define PASS3SEL(P, KN) \
    if (tid < 64) { \
        const int c0i = lane * 8; unsigned int s = 0; \
        _Pragma("unroll") for (int i = 0; i < 8; i++) s += hist[c0i + i]; \
        unsigned int suf = s; \
        _Pragma("unroll") for (int off = 1; off < 64; off <<= 1) { \
            unsigned int tv = __shfl_down(suf, off); if (lane + off < 64) suf += tv; } \
        unsigned int above = suf - s; \
        if (suf >= (KN) && above < (KN)) { \
            unsigned int cum = above; \
            for (int b = c0i + 7; ; b--) { \
                unsigned int c2 = hist[b]; \
                if (cum + c2 >= (KN)) { s_sel = ((P) << 9) | (unsigned int)b; s_kneed = (KN) - cum; s_eq = c2; break; } \
                cum += c2; } } } \
    __syncthreads();

__global__ __launch_bounds__(NT) __attribute__((amdgpu_waves_per_eu(4, 4)))
void md_fused_kernel(const float* __restrict__ Tt,
                     const float* __restrict__ U,
                     const float* __restrict__ D,
                     float* __restrict__ out,     // [B,N] mask
                     float* __restrict__ wout) {  // [B] weights
    const int row = blockIdx.x;
    const int tid = threadIdx.x;
    const int lane = tid & 63;

    const float* Ur = U + (size_t)row * NN;
    const float* Dr = D + (size_t)row * NN;
    float* Or = out + (size_t)row * NN;

    __shared__ unsigned int hist[8192];
    __shared__ unsigned int chunkSum[NT];
    __shared__ unsigned int bandU[CAP];
    __shared__ int bandIdx[CAP];
    __shared__ int s_tielist[1024];
    __shared__ unsigned int s_sel, s_kneed, s_eq;
    __shared__ int s_A, s_bandCnt, s_tiecnt, s_tieidx;

    // ---- per-thread k; f32 step-for-step like ref ----
    const float t = Tt[row];
    const float pf = (float)M_PI;
    float aa = pf * t;
    float bbv = aa * 0.5f;
    float c0 = (float)cos((double)bbv);
    float r  = 1.0f - c0;
    const int k = (int)(65536.0f * r);
    if (tid == 0) {
        float tadj = t * 0.998f + 0.001f;
        float arg  = (pf * tadj) * 0.5f;
        wout[row] = (float)(0.5 * M_PI) * (float)sin((double)arg);
    }

    if (k <= 0 || k >= NN) {
        const float fill = (k >= NN) ? 1.0f : 0.0f;
        float4 f4 = make_float4(fill, fill, fill, fill);
        for (int j = 0; j < 16; j++)
            *(float4*)(Or + j * 4096 + tid * 4) = f4;
        return;
    }
    const unsigned int kk = (unsigned int)k;

    uint4 v0, v1, v2, v3, v4, v5, v6, v7, v8, v9, v10, v11, v12, v13, v14, v15;

    for (int i = tid; i < 8192; i += NT) hist[i] = 0;
    if (tid == 0) { s_A = 0; s_bandCnt = 0; }
    __syncthreads();

    // ---- fast approx weights into named regs + 13-bit histogram ----
#define COMPF(J) { \
        int e = (J) * 4096 + tid * 4; \
        float4 u4 = *(const float4*)(Ur + e); \
        float4 d4 = *(const float4*)(Dr + e); \
        v##J.x = wfast(u4.x, d4.x); \
        v##J.y = wfast(u4.y, d4.y); \
        v##J.z = wfast(u4.z, d4.z); \
        v##J.w = wfast(u4.w, d4.w); \
        atomicAdd(&hist[v##J.x >> 19], 1u); \
        atomicAdd(&hist[v##J.y >> 19], 1u); \
        atomicAdd(&hist[v##J.z >> 19], 1u); \
        atomicAdd(&hist[v##J.w >> 19], 1u); }
    CHUNKS(COMPF)
#undef COMPF
    __syncthreads();

    PASS1SEL(kk)
    const unsigned int p13 = s_sel;
    const unsigned int kn1 = s_kneed;
    hist[tid] = 0;
    __syncthreads();
#define P2F(J) { \
        if ((v##J.x >> 19) == p13) atomicAdd(&hist[(v##J.x >> 9) & 1023u], 1u); \
        if ((v##J.y >> 19) == p13) atomicAdd(&hist[(v##J.y >> 9) & 1023u], 1u); \
        if ((v##J.z >> 19) == p13) atomicAdd(&hist[(v##J.z >> 9) & 1023u], 1u); \
        if ((v##J.w >> 19) == p13) atomicAdd(&hist[(v##J.w >> 9) & 1023u], 1u); }
    CHUNKS(P2F)
#undef P2F
    __syncthreads();
    PASS2SEL(p13, kn1)

    // ---- band bounds: approx-theta's 512-ulp bucket +/- margin ----
    const unsigned int p23 = s_sel;
    const unsigned int bktLo = p23 << 9;
    const unsigned int bktHi = bktLo | 511u;
    const float loF = sort2f(bktLo) - MARGIN;
    const float hiF = sort2f(bktHi) + MARGIN;
    const bool badBand = !(finite_f(loF) && finite_f(hiF));
    const unsigned int lo_u = f2sort(loF);
    const unsigned int hi_u = f2sort(hiF);

    // ---- count definite-ins (wa > hi) + gather band with exact re-eval ----
    {
        int cnt = 0;
#define ACNT1(X) cnt += (int)((X) > hi_u);
#define ACNT(J) ACNT1(v##J.x) ACNT1(v##J.y) ACNT1(v##J.z) ACNT1(v##J.w)
        CHUNKS(ACNT)
#undef ACNT
#undef ACNT1
#pragma unroll
        for (int off = 32; off >= 1; off >>= 1) cnt += __shfl_down(cnt, off);
        if (lane == 0) atomicAdd(&s_A, cnt);
    }
#define GATH1(J, C, CI) { unsigned int uu = v##J.C; \
        if (uu >= lo_u && uu <= hi_u) { \
            int slot = atomicAdd(&s_bandCnt, 1); \
            if (slot < CAP) { \
                int idx = (J) * 4096 + tid * 4 + (CI); \
                bandU[slot] = wexact(Ur[idx], Dr[idx]); \
                bandIdx[slot] = idx; } } }
#define GATH(J) GATH1(J, x, 0) GATH1(J, y, 1) GATH1(J, z, 2) GATH1(J, w, 3)
    CHUNKS(GATH)
#undef GATH
#undef GATH1
    __syncthreads();

    const int bandCnt = s_bandCnt;
    const int A = s_A;
    const int kb = k - A;
    const bool fallback = badBand || (bandCnt > CAP) || (kb < 0) || (kb > bandCnt);

    if (!fallback) {
        // ---- fast write: definite in/out by approx value, band by exact rank ----
#define MVF(u, idx) ((u) > hi_u ? 1.0f : ((u) < lo_u ? 0.0f : \
                     (band_in((idx), bandU, bandIdx, bandCnt, kb) ? 1.0f : 0.0f)))
#define WRF(J) { \
        int e = (J) * 4096 + tid * 4; \
        float4 m; \
        m.x = MVF(v##J.x, e + 0); \
        m.y = MVF(v##J.y, e + 1); \
        m.z = MVF(v##J.z, e + 2); \
        m.w = MVF(v##J.w, e + 3); \
        *(float4*)(Or + e) = m; }
        CHUNKS(WRF)
#undef WRF
#undef MVF
        return;
    }

    // ================= exact fallback (uniform branch, R4 algorithm) =========
    __syncthreads();
    for (int i = tid; i < 8192; i += NT) hist[i] = 0;
    __syncthreads();
#define COMPE(J) { \
        int e = (J) * 4096 + tid * 4; \
        float4 u4 = *(const float4*)(Ur + e); \
        float4 d4 = *(const float4*)(Dr + e); \
        v##J.x = wexact(u4.x, d4.x); \
        v##J.y = wexact(u4.y, d4.y); \
        v##J.z = wexact(u4.z, d4.z); \
        v##J.w = wexact(u4.w, d4.w); \
        atomicAdd(&hist[v##J.x >> 19], 1u); \
        atomicAdd(&hist[v##J.y >> 19], 1u); \
        atomicAdd(&hist[v##J.z >> 19], 1u); \
        atomicAdd(&hist[v##J.w >> 19], 1u); }
    CHUNKS(COMPE)
#undef COMPE
    __syncthreads();

    PASS1SEL(kk)
    const unsigned int q13 = s_sel;
    const unsigned int en1 = s_kneed;
    hist[tid] = 0;
    __syncthreads();
#define P2E(J) { \
        if ((v##J.x >> 19) == q13) atomicAdd(&hist[(v##J.x >> 9) & 1023u], 1u); \
        if ((v##J.y >> 19) == q13) atomicAdd(&hist[(v##J.y >> 9) & 1023u], 1u); \
        if ((v##J.z >> 19) == q13) atomicAdd(&hist[(v##J.z >> 9) & 1023u], 1u); \
        if ((v##J.w >> 19) == q13) atomicAdd(&hist[(v##J.w >> 9) & 1023u], 1u); }
    CHUNKS(P2E)
#undef P2E
    __syncthreads();
    PASS2SEL(q13, en1)

    const unsigned int q23 = s_sel;
    const unsigned int en2 = s_kneed;
    if (tid < 512) hist[tid] = 0;
    __syncthreads();
#define P3E(J) { \
        if ((v##J.x >> 9) == q23) atomicAdd(&hist[v##J.x & 511u], 1u); \
        if ((v##J.y >> 9) == q23) atomicAdd(&hist[v##J.y & 511u], 1u); \
        if ((v##J.z >> 9) == q23) atomicAdd(&hist[v##J.z & 511u], 1u); \
        if ((v##J.w >> 9) == q23) atomicAdd(&hist[v##J.w & 511u], 1u); }
    CHUNKS(P3E)
#undef P3E
    __syncthreads();
    PASS3SEL(q23, en2)

    const unsigned int theta = s_sel;
    const unsigned int kneedF = s_kneed, eqF = s_eq;
    const bool needOrder = (kneedF < eqF);
    int istar = NN;
    if (needOrder) {
        if (tid == 0) s_tiecnt = 0;
        __syncthreads();
#define TIE1(J, C, CI) if (v##J.C == theta) { \
            int pos = atomicAdd(&s_tiecnt, 1); \
            if (pos < 1024) s_tielist[pos] = (J) * 4096 + tid * 4 + (CI); }
#define TIE(J) TIE1(J, x, 0) TIE1(J, y, 1) TIE1(J, z, 2) TIE1(J, w, 3)
        CHUNKS(TIE)
#undef TIE
#undef TIE1
        __syncthreads();
        if (tid == 0) {
            int E = s_tiecnt; if (E > 1024) E = 1024;
            for (int aI = 1; aI < E; aI++) {
                int val = s_tielist[aI]; int bI = aI - 1;
                while (bI >= 0 && s_tielist[bI] > val) { s_tielist[bI + 1] = s_tielist[bI]; bI--; }
                s_tielist[bI + 1] = val;
            }
            int kk2 = (int)kneedF; if (kk2 > E) kk2 = E; if (kk2 < 1) kk2 = 1;
            s_tieidx = s_tielist[kk2 - 1];
        }
        __syncthreads();
        istar = s_tieidx;
    }

#define MVE(u, idx) ((((u) > theta) || ((u) == theta && (!needOrder || (idx) <= istar))) ? 1.0f : 0.0f)
#define WRE(J) { \
        int e = (J) * 4096 + tid * 4; \
        float4 m; \
        m.x = MVE(v##J.x, e + 0); \
        m.y = MVE(v##J.y, e + 1); \
        m.z = MVE(v##J.z, e + 2); \
        m.w = MVE(v##J.w, e + 3); \
        *(float4*)(Or + e) = m; }
    CHUNKS(WRE)
#undef WRE
#undef MVE
}

extern "C" void kernel_launch(void* const* d_in, const int* in_sizes, int n_in,
                              void* d_out, int out_size, void* d_ws, size_t ws_size,
                              hipStream_t stream) {
    // inputs: batch[B*N] i32 (unused), t[B] f32, U[B*N] f32, D[B*N] f32
    const float* T = (const float*)d_in[1];
    const float* U = (const float*)d_in[2];
    const float* D = (const float*)d_in[3];
    float* out = (float*)d_out;
    float* wout = out + (size_t)BB * NN;

    md_fused_kernel<<<BB, NT, 0, stream>>>(T, U, D, out, wout);
}

// Round 6
// 237.687 us; speedup vs baseline: 1.9225x; 1.9225x over previous
//
#include <hip/hip_runtime.h>
#include <math.h>

#define BB 256
#define NN 65536
#define NT 1024
#define CAP 2048
#define MARGIN 2e-3f

// Monotonic map: float order == uint order (ascending), and inverse
__device__ __forceinline__ unsigned int f2sort(float f) {
    unsigned int b = __float_as_uint(f);
    return (b & 0x80000000u) ? ~b : (b | 0x80000000u);
}
__device__ __forceinline__ float sort2f(unsigned int u) {
    unsigned int b = (u & 0x80000000u) ? (u & 0x7fffffffu) : ~u;
    return __uint_as_float(b);
}

// Bit-exact vs numpy f32 (f64 log rounded to f32) — band + fallback only
__device__ __forceinline__ unsigned int wexact(float u, float d) {
    float t1 = u + 1e-7f;
    float t2 = (float)log((double)t1);
    float t3 = (-t2) + 1e-7f;
    float G  = -(float)log((double)t3);
    float lgD = (float)log((double)d);
    return f2sort(G + lgD);
}

// Fast path: hw v_log_f32. |wfast - wexact| <= ~1.5e-4 abs (worst case |logD|~88);
// MARGIN = 2e-3 gives >10x safety. Fallback guards any violation structurally.
__device__ __forceinline__ unsigned int wfast(float u, float d) {
    float t1 = u + 1e-7f;
    float t3 = -__logf(t1) + 1e-7f;
    float G  = -__logf(t3);
    return f2sort(G + __logf(d));
}

__device__ __forceinline__ bool finite_f(float f) {
    return (__float_as_uint(f) & 0x7f800000u) != 0x7f800000u;
}

#define CHUNKS(OP) OP(0) OP(1) OP(2) OP(3) OP(4) OP(5) OP(6) OP(7) \
                   OP(8) OP(9) OP(10) OP(11) OP(12) OP(13) OP(14) OP(15)

#define PASS1SEL(KKV) \
    { const int b0 = tid * 8; unsigned int cs = 0; \
      _Pragma("unroll") for (int i = 0; i < 8; i++) cs += hist[b0 + i]; \
      chunkSum[tid] = cs; } \
    __syncthreads(); \
    if (tid < 64) { \
        const int c0i = lane * 16; unsigned int s = 0; \
        _Pragma("unroll") for (int i = 0; i < 16; i++) s += chunkSum[c0i + i]; \
        unsigned int suf = s; \
        _Pragma("unroll") for (int off = 1; off < 64; off <<= 1) { \
            unsigned int tv = __shfl_down(suf, off); if (lane + off < 64) suf += tv; } \
        unsigned int above = suf - s; \
        if (suf >= (KKV) && above < (KKV)) { \
            unsigned int cum = above; \
            for (int ci = c0i + 15; ci >= c0i; ci--) { \
                unsigned int cch = chunkSum[ci]; \
                if (cum + cch >= (KKV)) { \
                    for (int b = ci * 8 + 7; ; b--) { \
                        unsigned int c2 = hist[b]; \
                        if (cum + c2 >= (KKV)) { s_sel = (unsigned int)b; s_kneed = (KKV) - cum; s_eq = c2; break; } \
                        cum += c2; } \
                    break; } \
                cum += cch; } } } \
    __syncthreads();

#define PASS2SEL(P, KN) \
    if (tid < 64) { \
        const int c0i = lane * 16; unsigned int s = 0; \
        _Pragma("unroll") for (int i = 0; i < 16; i++) s += hist[c0i + i]; \
        unsigned int suf = s; \
        _Pragma("unroll") for (int off = 1; off < 64; off <<= 1) { \
            unsigned int tv = __shfl_down(suf, off); if (lane + off < 64) suf += tv; } \
        unsigned int above = suf - s; \
        if (suf >= (KN) && above < (KN)) { \
            unsigned int cum = above; \
            for (int b = c0i + 15; ; b--) { \
                unsigned int c2 = hist[b]; \
                if (cum + c2 >= (KN)) { s_sel = ((P) << 10) | (unsigned int)b; s_kneed = (KN) - cum; s_eq = c2; break; } \
                cum += c2; } } } \
    __syncthreads();

#define PASS3SEL(P, KN) \
    if (tid < 64) { \
        const int c0i = lane * 8; unsigned int s = 0; \
        _Pragma("unroll") for (int i = 0; i < 8; i++) s += hist[c0i + i]; \
        unsigned int suf = s; \
        _Pragma("unroll") for (int off = 1; off < 64; off <<= 1) { \
            unsigned int tv = __shfl_down(suf, off); if (lane + off < 64) suf += tv; } \
        unsigned int above = suf - s; \
        if (suf >= (KN) && above < (KN)) { \
            unsigned int cum = above; \
            for (int b = c0i + 7; ; b--) { \
                unsigned int c2 = hist[b]; \
                if (cum + c2 >= (KN)) { s_sel = ((P) << 9) | (unsigned int)b; s_kneed = (KN) - cum; s_eq = c2; break; } \
                cum += c2; } } } \
    __syncthreads();

__global__ __launch_bounds__(NT) __attribute__((amdgpu_waves_per_eu(4, 4)))
void md_fused_kernel(const float* __restrict__ Tt,
                     const float* __restrict__ U,
                     const float* __restrict__ D,
                     float* __restrict__ out,     // [B,N] mask
                     float* __restrict__ wout) {  // [B] weights
    const int row = blockIdx.x;
    const int tid = threadIdx.x;
    const int lane = tid & 63;

    const float* Ur = U + (size_t)row * NN;
    const float* Dr = D + (size_t)row * NN;
    float* Or = out + (size_t)row * NN;

    __shared__ unsigned int hist[8192];
    __shared__ unsigned int chunkSum[NT];
    __shared__ unsigned int bandU[CAP];
    __shared__ int bandIdx[CAP];
    __shared__ unsigned int bitmap[2048];     // 65536 decision bits for band
    __shared__ int s_tielist[1024];
    __shared__ unsigned int s_sel, s_kneed, s_eq;
    __shared__ int s_A, s_bandCnt, s_tiecnt, s_tieidx;

    // ---- per-thread k; f32 step-for-step like ref ----
    const float t = Tt[row];
    const float pf = (float)M_PI;
    float aa = pf * t;
    float bbv = aa * 0.5f;
    float c0 = (float)cos((double)bbv);
    float r  = 1.0f - c0;
    const int k = (int)(65536.0f * r);
    if (tid == 0) {
        float tadj = t * 0.998f + 0.001f;
        float arg  = (pf * tadj) * 0.5f;
        wout[row] = (float)(0.5 * M_PI) * (float)sin((double)arg);
    }

    if (k <= 0 || k >= NN) {
        const float fill = (k >= NN) ? 1.0f : 0.0f;
        float4 f4 = make_float4(fill, fill, fill, fill);
        for (int j = 0; j < 16; j++)
            *(float4*)(Or + j * 4096 + tid * 4) = f4;
        return;
    }
    const unsigned int kk = (unsigned int)k;

    uint4 v0, v1, v2, v3, v4, v5, v6, v7, v8, v9, v10, v11, v12, v13, v14, v15;

    for (int i = tid; i < 8192; i += NT) hist[i] = 0;
    if (tid == 0) { s_A = 0; s_bandCnt = 0; }
    __syncthreads();

    // ---- fast approx weights into named regs + 13-bit histogram ----
#define COMPF(J) { \
        int e = (J) * 4096 + tid * 4; \
        float4 u4 = *(const float4*)(Ur + e); \
        float4 d4 = *(const float4*)(Dr + e); \
        v##J.x = wfast(u4.x, d4.x); \
        v##J.y = wfast(u4.y, d4.y); \
        v##J.z = wfast(u4.z, d4.z); \
        v##J.w = wfast(u4.w, d4.w); \
        atomicAdd(&hist[v##J.x >> 19], 1u); \
        atomicAdd(&hist[v##J.y >> 19], 1u); \
        atomicAdd(&hist[v##J.z >> 19], 1u); \
        atomicAdd(&hist[v##J.w >> 19], 1u); }
    CHUNKS(COMPF)
#undef COMPF
    __syncthreads();

    PASS1SEL(kk)
    const unsigned int p13 = s_sel;
    const unsigned int kn1 = s_kneed;
    hist[tid] = 0;
    __syncthreads();
#define P2F(J) { \
        if ((v##J.x >> 19) == p13) atomicAdd(&hist[(v##J.x >> 9) & 1023u], 1u); \
        if ((v##J.y >> 19) == p13) atomicAdd(&hist[(v##J.y >> 9) & 1023u], 1u); \
        if ((v##J.z >> 19) == p13) atomicAdd(&hist[(v##J.z >> 9) & 1023u], 1u); \
        if ((v##J.w >> 19) == p13) atomicAdd(&hist[(v##J.w >> 9) & 1023u], 1u); }
    CHUNKS(P2F)
#undef P2F
    __syncthreads();
    PASS2SEL(p13, kn1)

    // ---- band bounds: approx-theta's 512-ulp bucket +/- margin ----
    const unsigned int p23 = s_sel;
    const float loF = sort2f(p23 << 9) - MARGIN;
    const float hiF = sort2f((p23 << 9) | 511u) + MARGIN;
    const bool badBand = !(finite_f(loF) && finite_f(hiF));
    const unsigned int lo_u = f2sort(loF);
    const unsigned int hi_u = f2sort(hiF);

    // ---- zero bitmap, count definite-ins, gather band INDICES only ----
    bitmap[tid] = 0;
    bitmap[tid + 1024] = 0;
    {
        int cnt = 0;
#define ACNT1(X) cnt += (int)((X) > hi_u);
#define ACNT(J) ACNT1(v##J.x) ACNT1(v##J.y) ACNT1(v##J.z) ACNT1(v##J.w)
        CHUNKS(ACNT)
#undef ACNT
#undef ACNT1
#pragma unroll
        for (int off = 32; off >= 1; off >>= 1) cnt += __shfl_down(cnt, off);
        if (lane == 0) atomicAdd(&s_A, cnt);
    }
#define GATH1(J, C, CI) { unsigned int uu = v##J.C; \
        if (uu >= lo_u && uu <= hi_u) { \
            int slot = atomicAdd(&s_bandCnt, 1); \
            if (slot < CAP) bandIdx[slot] = (J) * 4096 + tid * 4 + (CI); } }
#define GATH(J) GATH1(J, x, 0) GATH1(J, y, 1) GATH1(J, z, 2) GATH1(J, w, 3)
    CHUNKS(GATH)
#undef GATH
#undef GATH1
    __syncthreads();

    const int bandCnt = s_bandCnt;
    const int kb = k - s_A;
    const bool fallback = badBand || (bandCnt > CAP) || (kb < 0) || (kb > bandCnt);

    if (!fallback) {
        // exact re-eval of band elements (single code site, ~tens of elems)
        for (int j = tid; j < bandCnt; j += NT) {
            int idx = bandIdx[j];
            bandU[j] = wexact(Ur[idx], Dr[idx]);
        }
        __syncthreads();
        // stable rank (desc value, asc index); winners set their bitmap bit
        for (int j = tid; j < bandCnt; j += NT) {
            unsigned int me = bandU[j];
            int mi = bandIdx[j];
            int rk = 0;
            for (int i = 0; i < bandCnt; i++) {
                unsigned int o = bandU[i];
                rk += (int)((o > me) || (o == me && bandIdx[i] < mi));
            }
            if (rk < kb) atomicOr(&bitmap[mi >> 5], 1u << (mi & 31));
        }
        __syncthreads();
        // branch-free write: definite-in OR band-winner bit
        const int b0 = (tid & 7) * 4;
#define WRF(J) { \
        int e = (J) * 4096 + tid * 4; \
        unsigned int wb = bitmap[(J) * 128 + (tid >> 3)]; \
        float4 m; \
        m.x = ((v##J.x > hi_u) || ((wb >> (b0 + 0)) & 1u)) ? 1.0f : 0.0f; \
        m.y = ((v##J.y > hi_u) || ((wb >> (b0 + 1)) & 1u)) ? 1.0f : 0.0f; \
        m.z = ((v##J.z > hi_u) || ((wb >> (b0 + 2)) & 1u)) ? 1.0f : 0.0f; \
        m.w = ((v##J.w > hi_u) || ((wb >> (b0 + 3)) & 1u)) ? 1.0f : 0.0f; \
        *(float4*)(Or + e) = m; }
        CHUNKS(WRF)
#undef WRF
        return;
    }

    // ================= exact fallback (uniform branch, R4 algorithm) =========
    __syncthreads();
    for (int i = tid; i < 8192; i += NT) hist[i] = 0;
    __syncthreads();
#define COMPE(J) { \
        int e = (J) * 4096 + tid * 4; \
        float4 u4 = *(const float4*)(Ur + e); \
        float4 d4 = *(const float4*)(Dr + e); \
        v##J.x = wexact(u4.x, d4.x); \
        v##J.y = wexact(u4.y, d4.y); \
        v##J.z = wexact(u4.z, d4.z); \
        v##J.w = wexact(u4.w, d4.w); \
        atomicAdd(&hist[v##J.x >> 19], 1u); \
        atomicAdd(&hist[v##J.y >> 19], 1u); \
        atomicAdd(&hist[v##J.z >> 19], 1u); \
        atomicAdd(&hist[v##J.w >> 19], 1u); }
    CHUNKS(COMPE)
#undef COMPE
    __syncthreads();

    PASS1SEL(kk)
    const unsigned int q13 = s_sel;
    const unsigned int en1 = s_kneed;
    hist[tid] = 0;
    __syncthreads();
#define P2E(J) { \
        if ((v##J.x >> 19) == q13) atomicAdd(&hist[(v##J.x >> 9) & 1023u], 1u); \
        if ((v##J.y >> 19) == q13) atomicAdd(&hist[(v##J.y >> 9) & 1023u], 1u); \
        if ((v##J.z >> 19) == q13) atomicAdd(&hist[(v##J.z >> 9) & 1023u], 1u); \
        if ((v##J.w >> 19) == q13) atomicAdd(&hist[(v##J.w >> 9) & 1023u], 1u); }
    CHUNKS(P2E)
#undef P2E
    __syncthreads();
    PASS2SEL(q13, en1)

    const unsigned int q23 = s_sel;
    const unsigned int en2 = s_kneed;
    if (tid < 512) hist[tid] = 0;
    __syncthreads();
#define P3E(J) { \
        if ((v##J.x >> 9) == q23) atomicAdd(&hist[v##J.x & 511u], 1u); \
        if ((v##J.y >> 9) == q23) atomicAdd(&hist[v##J.y & 511u], 1u); \
        if ((v##J.z >> 9) == q23) atomicAdd(&hist[v##J.z & 511u], 1u); \
        if ((v##J.w >> 9) == q23) atomicAdd(&hist[v##J.w & 511u], 1u); }
    CHUNKS(P3E)
#undef P3E
    __syncthreads();
    PASS3SEL(q23, en2)

    const unsigned int theta = s_sel;
    const unsigned int kneedF = s_kneed, eqF = s_eq;
    const bool needOrder = (kneedF < eqF);
    int istar = NN;
    if (needOrder) {
        if (tid == 0) s_tiecnt = 0;
        __syncthreads();
#define TIE1(J, C, CI) if (v##J.C == theta) { \
            int pos = atomicAdd(&s_tiecnt, 1); \
            if (pos < 1024) s_tielist[pos] = (J) * 4096 + tid * 4 + (CI); }
#define TIE(J) TIE1(J, x, 0) TIE1(J, y, 1) TIE1(J, z, 2) TIE1(J, w, 3)
        CHUNKS(TIE)
#undef TIE
#undef TIE1
        __syncthreads();
        if (tid == 0) {
            int E = s_tiecnt; if (E > 1024) E = 1024;
            for (int aI = 1; aI < E; aI++) {
                int val = s_tielist[aI]; int bI = aI - 1;
                while (bI >= 0 && s_tielist[bI] > val) { s_tielist[bI + 1] = s_tielist[bI]; bI--; }
                s_tielist[bI + 1] = val;
            }
            int kk2 = (int)kneedF; if (kk2 > E) kk2 = E; if (kk2 < 1) kk2 = 1;
            s_tieidx = s_tielist[kk2 - 1];
        }
        __syncthreads();
        istar = s_tieidx;
    }

#define MVE(u, idx) ((((u) > theta) || ((u) == theta && (!needOrder || (idx) <= istar))) ? 1.0f : 0.0f)
#define WRE(J) { \
        int e = (J) * 4096 + tid * 4; \
        float4 m; \
        m.x = MVE(v##J.x, e + 0); \
        m.y = MVE(v##J.y, e + 1); \
        m.z = MVE(v##J.z, e + 2); \
        m.w = MVE(v##J.w, e + 3); \
        *(float4*)(Or + e) = m; }
    CHUNKS(WRE)
#undef WRE
#undef MVE
}

extern "C" void kernel_launch(void* const* d_in, const int* in_sizes, int n_in,
                              void* d_out, int out_size, void* d_ws, size_t ws_size,
                              hipStream_t stream) {
    // inputs: batch[B*N] i32 (unused), t[B] f32, U[B*N] f32, D[B*N] f32
    const float* T = (const float*)d_in[1];
    const float* U = (const float*)d_in[2];
    const float* D = (const float*)d_in[3];
    float* out = (float*)d_out;
    float* wout = out + (size_t)BB * NN;

    md_fused_kernel<<<BB, NT, 0, stream>>>(T, U, D, out, wout);
}